// Round 11
// baseline (326.705 us; speedup 1.0000x reference)
//
#include <hip/hip_runtime.h>

#define B_SZ 1024
#define H_SZ 2048
#define E_SZ 1024

typedef float  f32x4 __attribute__((ext_vector_type(4)));
typedef short  s16x8 __attribute__((ext_vector_type(8)));

__device__ __forceinline__ unsigned short f2bf(float f) {
    unsigned u = __float_as_uint(f);
    u = u + 0x7fffu + ((u >> 16) & 1u);   // RNE
    return (unsigned short)(u >> 16);
}
__device__ __forceinline__ float bf2f(unsigned short s) {
    return __uint_as_float(((unsigned)s) << 16);
}
__device__ __forceinline__ float sigm(float v) {
    return 1.0f / (1.0f + __expf(-v));
}
__device__ __forceinline__ unsigned cvtpk(float lo, float hi) {
    unsigned r;
    asm("v_cvt_pk_bf16_f32 %0, %1, %2" : "=v"(r) : "v"(lo), "v"(hi));
    return r;
}

__device__ __forceinline__ void gll(const unsigned short* g, unsigned short* l) {
    __builtin_amdgcn_global_load_lds(
        (const __attribute__((address_space(1))) unsigned int*)g,
        (__attribute__((address_space(3))) unsigned int*)l, 16, 0, 0);
}

// ---------------------------------------------------------------- cast pass
// x, h, 8 gate weights (162 MB). Why stays f32 (y_split f32 path).
struct CastArgs {
    const float*    src[10];
    unsigned short* dst[10];
    int             n[10];
};

__global__ __launch_bounds__(256) void cast_kernel(CastArgs a) {
    const int arr = blockIdx.y;
    const int n = a.n[arr];
    const float* __restrict__ s = a.src[arr];
    unsigned short* __restrict__ d = a.dst[arr];
    const int stride = gridDim.x * 256 * 4;
    for (int i = (blockIdx.x * 256 + threadIdx.x) * 4; i < n; i += stride) {
        float4 v = *(const float4*)(s + i);
        ushort4 o;
        o.x = f2bf(v.x); o.y = f2bf(v.y); o.z = f2bf(v.z); o.w = f2bf(v.w);
        *(ushort4*)(d + i) = o;
    }
}

// --------------------------------------------- gates + cell, fused kernel
// R8 geometry bit-for-bit (256 thr / 4 waves, BM=128, BN=128 = 4 gates x 32
// H-cols, BK=64, same swizzle/staging/fragments/epilogue). ONE change:
// double-buffered staging LDS (64KB, still 2 blocks/CU) with raw s_barriers
// and COUNTED s_waitcnt vmcnt(8) per K-step, unified 48-step E+H loop.
// This removes the compiler's full vmcnt(0) drain from 47 of 48 steps —
// the ~2000cy/step structural stall of the m97-class 2-barrier loop.
// Hazards: bar#1(k) separates stage(k) from reads(k); bar#2(k) separates
// reads(k,buf) from stage(k+2,buf) issued in step k+1. Tail: vmcnt(0) once.
struct GatesCellArgs {
    const unsigned short *Xb, *Hb, *Wxb, *Whb;
    const float *bias[4];
    const float *cin;
    float *c_out, *h_out;
    unsigned short *HnB;
};

__global__ __launch_bounds__(256, 2) void gates_cell_kernel(GatesCellArgs a) {
    __shared__ unsigned short smem[32768];   // [buf][lA 8K | lB 8K] x2 = 64KB
    unsigned short* lA = smem;               // + buf*8192
    unsigned short* lB = smem + 16384;       // + buf*8192

    const int t   = threadIdx.x;
    const int b   = blockIdx.x;
    const int xcd = b & 7;
    const int i_  = b >> 3;                 // 0..63 within XCD
    const int nt  = xcd * 8 + (i_ >> 3);    // 0..63 n-tile (32 H-cols)
    const int m0  = (i_ & 7) * 128;
    const int n0h = nt * 32;

    const size_t HE = (size_t)H_SZ * E_SZ, HH = (size_t)H_SZ * H_SZ;

    // staging addresses (R8-exact): chunk c = t + 256p -> row c>>3, col t&7
    const int srow = t >> 3;                              // 0..31
    const int scol = ((t & 7) ^ (srow & 7)) << 3;         // swizzled col
    const unsigned short* xaE = a.Xb + (size_t)(m0 + srow) * E_SZ + scol;
    const unsigned short* xaH = a.Hb + (size_t)(m0 + srow) * H_SZ + scol;
    const size_t stE = (size_t)32 * E_SZ, stH = (size_t)32 * H_SZ;
    const size_t bE  = (size_t)(n0h + srow) * E_SZ + scol;
    const size_t bH  = (size_t)(n0h + srow) * H_SZ + scol;
    const unsigned short* wE0 = a.Wxb + bE;
    const unsigned short* wE1 = a.Wxb + HE + bE;
    const unsigned short* wE2 = a.Wxb + 2 * HE + bE;
    const unsigned short* wE3 = a.Wxb + 3 * HE + bE;
    const unsigned short* wH0 = a.Whb + bH;
    const unsigned short* wH1 = a.Whb + HH + bH;
    const unsigned short* wH2 = a.Whb + 2 * HH + bH;
    const unsigned short* wH3 = a.Whb + 3 * HH + bH;

    auto stage = [&](int kk, int buf) {   // 8 gll: 4 A-chunks + 4 gate-B
        unsigned short* dA = lA + buf * 8192 + t * 8;
        unsigned short* dB = lB + buf * 8192 + t * 8;
        if (kk < 16) {
            const int k = kk * 64;
            gll(xaE + k,           dA);
            gll(xaE + k + stE,     dA + 2048);
            gll(xaE + k + 2 * stE, dA + 4096);
            gll(xaE + k + 3 * stE, dA + 6144);
            gll(wE0 + k, dB);        gll(wE1 + k, dB + 2048);
            gll(wE2 + k, dB + 4096); gll(wE3 + k, dB + 6144);
        } else {
            const int k = (kk - 16) * 64;
            gll(xaH + k,           dA);
            gll(xaH + k + stH,     dA + 2048);
            gll(xaH + k + 2 * stH, dA + 4096);
            gll(xaH + k + 3 * stH, dA + 6144);
            gll(wH0 + k, dB);        gll(wH1 + k, dB + 2048);
            gll(wH2 + k, dB + 4096); gll(wH3 + k, dB + 6144);
        }
    };

    // fragment constants (R8-exact)
    const int lane = t & 63, w = t >> 6;
    const int wr = (w >> 1) << 6, wc = (w & 1) << 6;
    const int lr = lane & 15, q4 = lane >> 4;
    const int cb0 = ((q4    ) ^ (lr & 7)) << 3;
    const int cb1 = ((4 + q4) ^ (lr & 7)) << 3;

    f32x4 acc[4][4] = {};

    auto compute = [&](int buf) {
        const unsigned short* pA = lA + buf * 8192;
        const unsigned short* pB = lB + buf * 8192;
#pragma unroll
        for (int ks = 0; ks < 2; ++ks) {
            const int cb = ks ? cb1 : cb0;
            s16x8 af[4], bfr[4];
#pragma unroll
            for (int i = 0; i < 4; ++i)
                af[i] = *(const s16x8*)(pA + (wr + i * 16 + lr) * 64 + cb);
#pragma unroll
            for (int j = 0; j < 4; ++j)
                bfr[j] = *(const s16x8*)(pB + (wc + j * 16 + lr) * 64 + cb);
#pragma unroll
            for (int i = 0; i < 4; ++i)
#pragma unroll
                for (int j = 0; j < 4; ++j)
                    acc[i][j] = __builtin_amdgcn_mfma_f32_16x16x32_bf16(
                        af[i], bfr[j], acc[i][j], 0, 0, 0);
        }
    };

    // prologue
    stage(0, 0);
    // main loop: steps 0..46 prefetch step+1; counted vmcnt(8) (tile kk done,
    // tile kk+1's 8 gll stay in flight). Raw barriers — no compiler drain.
#pragma unroll 1
    for (int kk = 0; kk < 47; ++kk) {
        stage(kk + 1, (kk + 1) & 1);
        asm volatile("s_waitcnt vmcnt(8)" ::: "memory");
        asm volatile("s_barrier" ::: "memory");
        compute(kk & 1);
        asm volatile("s_barrier" ::: "memory");
    }
    // tail: step 47
    asm volatile("s_waitcnt vmcnt(0)" ::: "memory");
    asm volatile("s_barrier" ::: "memory");
    compute(1);
    __syncthreads();   // all frag reads done; smem reusable as exchange

    // ---- epilogue 1: bias + activation -> exchange [128][136-stride]
    const int rq = (lane >> 4) << 2;
#pragma unroll
    for (int j = 0; j < 4; ++j) {
        const int col = wc + j * 16 + lr;       // 0..127; gate = col>>5
        const int q   = col >> 5;
        const float bv = a.bias[q][n0h + (col & 31)];
#pragma unroll
        for (int i = 0; i < 4; ++i) {
#pragma unroll
            for (int r = 0; r < 4; ++r) {
                const int row = wr + i * 16 + rq + r;
                const float v = acc[i][j][r] + bv;
                const float act = (q == 1) ? tanhf(v) : sigm(v);
                smem[row * 136 + col] = f2bf(act);
            }
        }
    }
    __syncthreads();

    // ---- epilogue 2: cell update, 16 h-elems/thread
    {
        const int row = t >> 1;          // 0..127
        const int hl0 = (t & 1) * 16;    // 0 or 16 within the 32 H-cols
        const unsigned short* ex = smem + row * 136;
        s16x8 i0 = *(const s16x8*)(ex + hl0);
        s16x8 i1 = *(const s16x8*)(ex + hl0 + 8);
        s16x8 g0 = *(const s16x8*)(ex + 32 + hl0);
        s16x8 g1 = *(const s16x8*)(ex + 32 + hl0 + 8);
        s16x8 f0 = *(const s16x8*)(ex + 64 + hl0);
        s16x8 f1 = *(const s16x8*)(ex + 64 + hl0 + 8);
        s16x8 o0 = *(const s16x8*)(ex + 96 + hl0);
        s16x8 o1 = *(const s16x8*)(ex + 96 + hl0 + 8);

        const size_t gidx = (size_t)(m0 + row) * H_SZ + n0h + hl0;
        float cn[16], hn[16];
#pragma unroll
        for (int k = 0; k < 16; ++k) {
            const float iv = bf2f((unsigned short)(k < 8 ? i0[k] : i1[k - 8]));
            const float gv = bf2f((unsigned short)(k < 8 ? g0[k] : g1[k - 8]));
            const float fv = bf2f((unsigned short)(k < 8 ? f0[k] : f1[k - 8]));
            const float ov = bf2f((unsigned short)(k < 8 ? o0[k] : o1[k - 8]));
            const float cv = a.cin[gidx + k];
            cn[k] = fv * cv + iv * gv;
            hn[k] = ov * cn[k];
        }
#pragma unroll
        for (int k = 0; k < 16; k += 4) {
            *(float4*)(a.c_out + gidx + k) = make_float4(cn[k], cn[k+1], cn[k+2], cn[k+3]);
            *(float4*)(a.h_out + gidx + k) = make_float4(hn[k], hn[k+1], hn[k+2], hn[k+3]);
            ushort4 hb;
            hb.x = f2bf(hn[k]);   hb.y = f2bf(hn[k+1]);
            hb.z = f2bf(hn[k+2]); hb.w = f2bf(hn[k+3]);
            *(ushort4*)(a.HnB + gidx + k) = hb;
        }
    }
}

// ---------------- y GEMM: BK=128 core, f32 Wy direct (R8-measured) -------
__device__ __forceinline__ void gemm_bk128(
    const unsigned short* __restrict__ A,
    const float* __restrict__ W,
    int ld, int kLen, int m0, int n0,
    unsigned short* lA, unsigned short* lB,
    f32x4 acc[4][4], int t)
{
    const int lane = t & 63;
    const int w    = t >> 6;
    const int wr   = (w >> 1) << 6;
    const int wc   = (w & 1) << 6;
    const int lr   = lane & 15;
    const int q4   = lane >> 4;

    const int srow = t >> 4;
    const int sblk = ((t & 15) ^ srow) << 3;
    const unsigned short* gA = A + (size_t)(m0 + srow) * ld + sblk;
    const float*          gW = W + (size_t)(n0 + srow) * ld + sblk;
    const size_t st16 = (size_t)16 * ld;

    f32x4 f0[8], f1[8];
#pragma unroll
    for (int p = 0; p < 8; ++p) {
        const float* s = gW + p * st16;
        f0[p] = *(const f32x4*)(s);
        f1[p] = *(const f32x4*)(s + 4);
    }

    for (int k0 = 0; k0 < kLen; k0 += 128) {
#pragma unroll
        for (int p = 0; p < 8; ++p) {
            uint4 pk;
            pk.x = cvtpk(f0[p].x, f0[p].y);
            pk.y = cvtpk(f0[p].z, f0[p].w);
            pk.z = cvtpk(f1[p].x, f1[p].y);
            pk.w = cvtpk(f1[p].z, f1[p].w);
            *(uint4*)(lB + (t + 256 * p) * 8) = pk;
        }
#pragma unroll
        for (int p = 0; p < 8; ++p)
            gll(gA + k0 + p * st16, lA + (t + 256 * p) * 8);
        __syncthreads();

        if (k0 + 128 < kLen) {
#pragma unroll
            for (int p = 0; p < 8; ++p) {
                const float* s = gW + (k0 + 128) + p * st16;
                f0[p] = *(const f32x4*)(s);
                f1[p] = *(const f32x4*)(s + 4);
            }
        }

#pragma unroll
        for (int ks = 0; ks < 4; ++ks) {
            s16x8 af[4], bfr[4];
#pragma unroll
            for (int i = 0; i < 4; ++i) {
                const int ra = wr + i * 16 + lr;
                af[i] = *(const s16x8*)(lA + ra * 128 +
                         ((((ks << 2) + q4) ^ (ra & 15)) << 3));
            }
#pragma unroll
            for (int j = 0; j < 4; ++j) {
                const int rb = wc + j * 16 + lr;
                bfr[j] = *(const s16x8*)(lB + rb * 128 +
                          ((((ks << 2) + q4) ^ (rb & 15)) << 3));
            }
#pragma unroll
            for (int i = 0; i < 4; ++i)
#pragma unroll
                for (int j = 0; j < 4; ++j)
                    acc[i][j] = __builtin_amdgcn_mfma_f32_16x16x32_bf16(
                        af[i], bfr[j], acc[i][j], 0, 0, 0);
        }
        __syncthreads();
    }
}

__global__ __launch_bounds__(256, 2) void y_split_kernel(
    const unsigned short* __restrict__ Hn,
    const float* __restrict__ Wy,
    float* __restrict__ part)
{
    __shared__ unsigned short lA[128 * 128];
    __shared__ unsigned short lB[128 * 128];
    const int t   = threadIdx.x;
    const int b   = blockIdx.x;
    const int xcd = b & 7;
    const int i_  = b >> 3;
    const int ns  = xcd * 4 + (i_ >> 3);
    const int m0  = (i_ & 7) * 128;
    const int n0  = (ns >> 2) * 128;
    const int s   = ns & 3;

    f32x4 acc[4][4] = {};
    gemm_bk128(Hn + s * 512, Wy + s * 512, H_SZ, 512, m0, n0, lA, lB, acc, t);

    const int lane = t & 63, w = t >> 6;
    const int wr = (w >> 1) << 6, wc = (w & 1) << 6;
    const int lr = lane & 15, rq = (lane >> 4) << 2;
    float* P = part + (size_t)s * B_SZ * E_SZ;
#pragma unroll
    for (int i = 0; i < 4; ++i) {
#pragma unroll
        for (int j = 0; j < 4; ++j) {
            const int n = n0 + wc + j * 16 + lr;
#pragma unroll
            for (int r = 0; r < 4; ++r) {
                const int m = m0 + wr + i * 16 + rq + r;
                P[(size_t)m * E_SZ + n] = acc[i][j][r];
            }
        }
    }
}

__global__ __launch_bounds__(256) void y_reduce_kernel(
    const float* __restrict__ part, const float* __restrict__ by,
    float* __restrict__ yout)
{
    const size_t BE = (size_t)B_SZ * E_SZ;
    const int idx = (blockIdx.x * 256 + threadIdx.x) * 4;
    float4 a = *(const float4*)(part + idx);
    float4 b2 = *(const float4*)(part + BE + idx);
    float4 c2 = *(const float4*)(part + 2 * BE + idx);
    float4 d2 = *(const float4*)(part + 3 * BE + idx);
    const int col = idx & (E_SZ - 1);
    float4 bv = *(const float4*)(by + col);
    float4 o;
    o.x = tanhf(a.x + b2.x + c2.x + d2.x + bv.x);
    o.y = tanhf(a.y + b2.y + c2.y + d2.y + bv.y);
    o.z = tanhf(a.z + b2.z + c2.z + d2.z + bv.z);
    o.w = tanhf(a.w + b2.w + c2.w + d2.w + bv.w);
    *(float4*)(yout + idx) = o;
}

// ---------------------------------------------------------------- launch
extern "C" void kernel_launch(void* const* d_in, const int* in_sizes, int n_in,
                              void* d_out, int out_size, void* d_ws, size_t ws_size,
                              hipStream_t stream) {
    const float* x   = (const float*)d_in[0];
    const float* c   = (const float*)d_in[1];
    const float* h   = (const float*)d_in[2];
    const float* Wxi = (const float*)d_in[3];
    const float* Whi = (const float*)d_in[4];
    const float* Bi  = (const float*)d_in[5];
    const float* Wxg = (const float*)d_in[6];
    const float* Whg = (const float*)d_in[7];
    const float* Bg  = (const float*)d_in[8];
    const float* Wxf = (const float*)d_in[9];
    const float* Whf = (const float*)d_in[10];
    const float* Bf  = (const float*)d_in[11];
    const float* Wxo = (const float*)d_in[12];
    const float* Who = (const float*)d_in[13];
    const float* Bo  = (const float*)d_in[14];
    const float* Why = (const float*)d_in[15];
    const float* By  = (const float*)d_in[16];

    const size_t BE = (size_t)B_SZ * E_SZ, BH = (size_t)B_SZ * H_SZ;
    const size_t HE = (size_t)H_SZ * E_SZ, HH = (size_t)H_SZ * H_SZ;

    unsigned short* ws  = (unsigned short*)d_ws;
    unsigned short* Xb  = ws;                 // BE bf16
    unsigned short* Hb  = Xb + BE;            // BH bf16
    unsigned short* Wxb = Hb + BH;            // 4*HE bf16
    unsigned short* Whb = Wxb + 4 * HE;       // 4*HH bf16
    unsigned short* HnB = Whb + 4 * HH;       // BH bf16
    float*          ypart = (float*)(HnB + BH); // 4*BE f32

    CastArgs ca;
    ca.src[0] = x;   ca.dst[0] = Xb;          ca.n[0] = (int)BE;
    ca.src[1] = h;   ca.dst[1] = Hb;          ca.n[1] = (int)BH;
    ca.src[2] = Wxi; ca.dst[2] = Wxb;         ca.n[2] = (int)HE;
    ca.src[3] = Wxg; ca.dst[3] = Wxb + HE;    ca.n[3] = (int)HE;
    ca.src[4] = Wxf; ca.dst[4] = Wxb + 2*HE;  ca.n[4] = (int)HE;
    ca.src[5] = Wxo; ca.dst[5] = Wxb + 3*HE;  ca.n[5] = (int)HE;
    ca.src[6] = Whi; ca.dst[6] = Whb;         ca.n[6] = (int)HH;
    ca.src[7] = Whg; ca.dst[7] = Whb + HH;    ca.n[7] = (int)HH;
    ca.src[8] = Whf; ca.dst[8] = Whb + 2*HH;  ca.n[8] = (int)HH;
    ca.src[9] = Who; ca.dst[9] = Whb + 3*HH;  ca.n[9] = (int)HH;
    hipLaunchKernelGGL(cast_kernel, dim3(512, 10), dim3(256), 0, stream, ca);

    float* y_out = (float*)d_out;
    float* c_out = y_out + BE;
    float* h_out = c_out + BH;

    GatesCellArgs ga;
    ga.Xb = Xb; ga.Hb = Hb; ga.Wxb = Wxb; ga.Whb = Whb;
    ga.bias[0] = Bi; ga.bias[1] = Bg; ga.bias[2] = Bf; ga.bias[3] = Bo;
    ga.cin = c; ga.c_out = c_out; ga.h_out = h_out; ga.HnB = HnB;
    hipLaunchKernelGGL(gates_cell_kernel, dim3(512), dim3(256), 0, stream, ga);

    hipLaunchKernelGGL(y_split_kernel, dim3(256), dim3(256), 0, stream,
                       HnB, Why, ypart);
    hipLaunchKernelGGL(y_reduce_kernel, dim3((unsigned)(BE / 1024)), dim3(256), 0, stream,
                       ypart, By, y_out);
}